// Round 6
// baseline (387.034 us; speedup 1.0000x reference)
//
#include <hip/hip_runtime.h>
#include <hip/hip_bf16.h>

// PatchIoULoss: B=16, C=1, H=W=1024, patch 64x64, stride 32x32 -> Ho=Wo=31.
// Window(i,j) = sum of 2x2 group of non-overlapping 32x32 block sums.
// Fused single kernel: per-block sums + last-block-done finalize.

#define Hdim 1024
#define Wdim 1024
#define NBLK 32          // 32x32 blocks per image per dim
#define HO 31
#define WO 31
#define EPSF 1e-7f

typedef float fx4 __attribute__((ext_vector_type(4)));

__device__ __forceinline__ float agload(const float* p) {
    // agent-scope load: bypasses this XCD's (possibly stale) L2 line
    return __hip_atomic_load(p, __ATOMIC_RELAXED, __HIP_MEMORY_SCOPE_AGENT);
}
__device__ __forceinline__ void agstore(float* p, float v) {
    // agent-scope store: visible at device coherence point (L3)
    __hip_atomic_store(p, v, __ATOMIC_RELAXED, __HIP_MEMORY_SCOPE_AGENT);
}

// grid = B * 32 strips * 4 column-quarters = 2048 blocks; 256 threads each.
// Both input streams NONTEMPORAL (proven best: cache policy can't beat the
// ~4.6 TB/s read path; NT avoids L2/L3 churn entirely).
__global__ __launch_bounds__(256) void fused_patch_iou_kernel(
    const float* __restrict__ pred, const float* __restrict__ targ,
    float* __restrict__ sp, float* __restrict__ st, float* __restrict__ si,
    unsigned* __restrict__ cnt, float* __restrict__ out, int B) {
    const int blk = blockIdx.x;
    const int q = blk & 3;           // column quarter 0..3
    const int strip = (blk >> 2) & 31;
    const int b = blk >> 7;          // image
    const int t = threadIdx.x;       // 0..255
    const int wid = t >> 6;          // wave 0..3
    const int lane = t & 63;

    const fx4* __restrict__ p4 =
        reinterpret_cast<const fx4*>(pred) + (size_t)b * (Hdim * Wdim / 4)
        + (size_t)strip * 32 * (Wdim / 4) + q * 64;
    const fx4* __restrict__ g4 =
        reinterpret_cast<const fx4*>(targ) + (size_t)b * (Hdim * Wdim / 4)
        + (size_t)strip * 32 * (Wdim / 4) + q * 64;

    float s_p = 0.f, s_t = 0.f, s_i = 0.f;
#pragma unroll
    for (int i = 0; i < 8; ++i) {
        const int idx = (4 * i + wid) * (Wdim / 4) + lane;
        fx4 p = __builtin_nontemporal_load(&p4[idx]);
        fx4 g = __builtin_nontemporal_load(&g4[idx]);
        s_p += (p.x + p.y) + (p.z + p.w);
        s_t += (g.x + g.y) + (g.z + g.w);
        s_i += p.x * g.x + p.y * g.y + p.z * g.z + p.w * g.w;
    }
    // Reduce the 8 lanes of each column-tile (lanes 8k..8k+7, same wave).
#pragma unroll
    for (int off = 4; off >= 1; off >>= 1) {
        s_p += __shfl_down(s_p, off, 64);
        s_t += __shfl_down(s_t, off, 64);
        s_i += __shfl_down(s_i, off, 64);
    }
    // Cross-wave reduce: 4 waves x 8 tiles per quantity.
    __shared__ float redp[4][8], redt[4][8], redi[4][8];
    if ((lane & 7) == 0) {
        const int tile = lane >> 3;  // 0..7
        redp[wid][tile] = s_p;
        redt[wid][tile] = s_t;
        redi[wid][tile] = s_i;
    }
    __syncthreads();
    if (t < 8) {
        const int idx = b * (NBLK * NBLK) + strip * NBLK + q * 8 + t;
        agstore(&sp[idx], (redp[0][t] + redp[1][t]) + (redp[2][t] + redp[3][t]));
        agstore(&st[idx], (redt[0][t] + redt[1][t]) + (redt[2][t] + redt[3][t]));
        agstore(&si[idx], (redi[0][t] + redi[1][t]) + (redi[2][t] + redi[3][t]));
    }

    // ---- last-block-done: the final block to retire runs the finalize ----
    __shared__ int lastFlag;
    __threadfence();
    __syncthreads();
    if (t == 0) {
        unsigned old = atomicAdd(cnt, 1u);
        lastFlag = (old == (unsigned)(gridDim.x - 1));
    }
    __syncthreads();
    if (!lastFlag) return;

    __threadfence();
    const int nwin = B * HO * WO;
    float acc = 0.f;
    for (int w = t; w < nwin; w += 256) {
        const int bb = w / (HO * WO);
        const int rem = w - bb * (HO * WO);
        const int i = rem / WO;
        const int j = rem - i * WO;
        const int base = bb * (NBLK * NBLK) + i * NBLK + j;
        const float inter = (agload(&si[base]) + agload(&si[base + 1]))
                          + (agload(&si[base + NBLK]) + agload(&si[base + NBLK + 1]));
        const float psum  = (agload(&sp[base]) + agload(&sp[base + 1]))
                          + (agload(&sp[base + NBLK]) + agload(&sp[base + NBLK + 1]));
        const float tsum  = (agload(&st[base]) + agload(&st[base + 1]))
                          + (agload(&st[base + NBLK]) + agload(&st[base + NBLK + 1]));
        const float uni = psum + tsum - inter;
        acc += 1.0f - (inter + EPSF) / (uni + EPSF);
    }
    // wave reduce within the finalizing block
#pragma unroll
    for (int off = 32; off >= 1; off >>= 1) acc += __shfl_down(acc, off, 64);
    __shared__ float redf[4];
    if ((t & 63) == 0) redf[t >> 6] = acc;
    __syncthreads();
    if (t == 0) {
        const float s = (redf[0] + redf[1]) + (redf[2] + redf[3]);
        out[0] = s / (float)nwin;
    }
}

extern "C" void kernel_launch(void* const* d_in, const int* in_sizes, int n_in,
                              void* d_out, int out_size, void* d_ws, size_t ws_size,
                              hipStream_t stream) {
    const float* pred = (const float*)d_in[0];
    const float* targ = (const float*)d_in[1];
    float* out = (float*)d_out;

    const int B = in_sizes[0] / (Hdim * Wdim);   // 16
    const int nblocks = B * NBLK * NBLK;         // block sums per quantity

    float* sp = (float*)d_ws;
    float* st = sp + nblocks;
    float* si = st + nblocks;
    unsigned* cnt = (unsigned*)(si + nblocks);

    hipMemsetAsync(cnt, 0, sizeof(unsigned), stream);
    fused_patch_iou_kernel<<<dim3(B * 32 * 4), dim3(256), 0, stream>>>(
        pred, targ, sp, st, si, cnt, out, B);
}

// Round 7
// 36.805 us; speedup vs baseline: 10.5158x; 10.5158x over previous
//
#include <hip/hip_runtime.h>
#include <hip/hip_bf16.h>

// PatchIoULoss: B=16, C=1, H=W=1024, patch 64x64, stride 32x32 -> Ho=Wo=31.
// Window(i,j) = sum of 2x2 group of non-overlapping 32x32 block sums.
// Two kernels (fused last-block-done version regressed 10x: per-block
// device fences -> L2 writeback/invalidate storm. Do not fuse.)

#define Hdim 1024
#define Wdim 1024
#define NBLK 32          // 32x32 blocks per image per dim
#define HO 31
#define WO 31
#define EPSF 1e-7f

typedef float fx4 __attribute__((ext_vector_type(4)));

// Kernel 1: per-block(32x32) sums of pred, target, pred*target.
// grid = B * 32 strips = 512 blocks; 256 threads. Block sweeps its strip
// fully contiguously (128 KB per stream). Loads are NONTEMPORAL and staged
// in batches of 8 per stream: 16 loads in flight per wave, and the block's
// request stream alternates pred/targ at ~32 KB granularity instead of
// 16 B -> DRAM row locality. Thread t's float4-col = t -> col-tile = t>>3
// (8 lanes/tile), so full 32x32 block sums come from an 8-lane shuffle,
// no LDS needed.
__global__ __launch_bounds__(256) void block_sums_kernel(
    const float* __restrict__ pred, const float* __restrict__ targ,
    float* __restrict__ sp, float* __restrict__ st, float* __restrict__ si) {
    const int blk = blockIdx.x;      // 0..511
    const int b = blk >> 5;          // image
    const int strip = blk & 31;      // row-block 0..31
    const int t = threadIdx.x;       // 0..255 (= float4 column)

    const size_t base4 = ((size_t)b * (Hdim * Wdim) + (size_t)strip * 32 * Wdim) / 4;
    const fx4* __restrict__ p4 = reinterpret_cast<const fx4*>(pred) + base4 + t;
    const fx4* __restrict__ g4 = reinterpret_cast<const fx4*>(targ) + base4 + t;

    float s_p = 0.f, s_t = 0.f, s_i = 0.f;
    for (int batch = 0; batch < 4; ++batch) {
        fx4 P[8], G[8];
#pragma unroll
        for (int i = 0; i < 8; ++i)
            P[i] = __builtin_nontemporal_load(p4 + (size_t)(batch * 8 + i) * 256);
#pragma unroll
        for (int i = 0; i < 8; ++i)
            G[i] = __builtin_nontemporal_load(g4 + (size_t)(batch * 8 + i) * 256);
#pragma unroll
        for (int i = 0; i < 8; ++i) {
            s_p += (P[i].x + P[i].y) + (P[i].z + P[i].w);
            s_t += (G[i].x + G[i].y) + (G[i].z + G[i].w);
            s_i += P[i].x * G[i].x + P[i].y * G[i].y + P[i].z * G[i].z + P[i].w * G[i].w;
        }
    }
    // Reduce the 8 lanes of each column-tile (lanes 8k..8k+7, same wave).
#pragma unroll
    for (int off = 4; off >= 1; off >>= 1) {
        s_p += __shfl_down(s_p, off, 64);
        s_t += __shfl_down(s_t, off, 64);
        s_i += __shfl_down(s_i, off, 64);
    }
    if ((t & 7) == 0) {
        const int ct = t >> 3;       // column-tile 0..31
        const int idx = b * (NBLK * NBLK) + strip * NBLK + ct;
        sp[idx] = s_p;
        st[idx] = s_t;
        si[idx] = s_i;
    }
}

// Kernel 2: combine 2x2 block sums per window, compute loss, mean over all.
// Single block of 1024 threads; B*31*31 = 15376 windows (15 iters/thread).
__global__ __launch_bounds__(1024) void finalize_kernel(
    const float* __restrict__ sp, const float* __restrict__ st,
    const float* __restrict__ si, float* __restrict__ out, int B) {
    const int t = threadIdx.x;
    const int nwin = B * HO * WO;
    float acc = 0.f;
    for (int w = t; w < nwin; w += 1024) {
        const int b = w / (HO * WO);
        const int rem = w - b * (HO * WO);
        const int i = rem / WO;
        const int j = rem - i * WO;
        const int base = b * (NBLK * NBLK) + i * NBLK + j;
        const float inter = (si[base] + si[base + 1]) + (si[base + NBLK] + si[base + NBLK + 1]);
        const float psum  = (sp[base] + sp[base + 1]) + (sp[base + NBLK] + sp[base + NBLK + 1]);
        const float tsum  = (st[base] + st[base + 1]) + (st[base + NBLK] + st[base + NBLK + 1]);
        const float uni = psum + tsum - inter;
        acc += 1.0f - (inter + EPSF) / (uni + EPSF);
    }
    // wave reduce
#pragma unroll
    for (int off = 32; off >= 1; off >>= 1) acc += __shfl_down(acc, off, 64);
    __shared__ float red[16];
    if ((t & 63) == 0) red[t >> 6] = acc;
    __syncthreads();
    if (t == 0) {
        float s = 0.f;
#pragma unroll
        for (int k = 0; k < 16; ++k) s += red[k];
        out[0] = s / (float)nwin;
    }
}

extern "C" void kernel_launch(void* const* d_in, const int* in_sizes, int n_in,
                              void* d_out, int out_size, void* d_ws, size_t ws_size,
                              hipStream_t stream) {
    const float* pred = (const float*)d_in[0];
    const float* targ = (const float*)d_in[1];
    float* out = (float*)d_out;

    const int B = in_sizes[0] / (Hdim * Wdim);   // 16
    const int nblocks = B * NBLK * NBLK;         // block sums per quantity

    float* sp = (float*)d_ws;
    float* st = sp + nblocks;
    float* si = st + nblocks;

    block_sums_kernel<<<dim3(B * 32), dim3(256), 0, stream>>>(pred, targ, sp, st, si);
    finalize_kernel<<<dim3(1), dim3(1024), 0, stream>>>(sp, st, si, out, B);
}

// Round 8
// 31.187 us; speedup vs baseline: 12.4100x; 1.1801x over previous
//
#include <hip/hip_runtime.h>
#include <hip/hip_bf16.h>

// PatchIoULoss: B=16, C=1, H=W=1024, patch 64x64, stride 32x32 -> Ho=Wo=31.
// Window(i,j) = sum of 2x2 group of non-overlapping 32x32 block sums.
// Two kernels. Read path measured pinned at ~4.3 TB/s (NT best); finalize
// parallelized 16-wide with float atomicAdd (noise ~1e-6 << 1.3e-2 thresh).
// Do NOT fuse with per-block device fences (round 6: 10x regression).

#define Hdim 1024
#define Wdim 1024
#define NBLK 32          // 32x32 blocks per image per dim
#define HO 31
#define WO 31
#define EPSF 1e-7f

typedef float fx4 __attribute__((ext_vector_type(4)));

// Kernel 1: per-block(32x32) sums of pred, target, pred*target.
// grid = B * 32 strips = 512 blocks; 256 threads. Block sweeps its strip
// fully contiguously (128 KB per stream). NT loads staged 8-deep per
// stream (16 in flight/wave). Thread t's float4-col = t -> col-tile = t>>3
// (8 lanes/tile): full 32x32 block sums via 8-lane shuffle, no LDS.
__global__ __launch_bounds__(256) void block_sums_kernel(
    const float* __restrict__ pred, const float* __restrict__ targ,
    float* __restrict__ sp, float* __restrict__ st, float* __restrict__ si) {
    const int blk = blockIdx.x;      // 0..511
    const int b = blk >> 5;          // image
    const int strip = blk & 31;      // row-block 0..31
    const int t = threadIdx.x;       // 0..255 (= float4 column)

    const size_t base4 = ((size_t)b * (Hdim * Wdim) + (size_t)strip * 32 * Wdim) / 4;
    const fx4* __restrict__ p4 = reinterpret_cast<const fx4*>(pred) + base4 + t;
    const fx4* __restrict__ g4 = reinterpret_cast<const fx4*>(targ) + base4 + t;

    float s_p = 0.f, s_t = 0.f, s_i = 0.f;
    for (int batch = 0; batch < 4; ++batch) {
        fx4 P[8], G[8];
#pragma unroll
        for (int i = 0; i < 8; ++i)
            P[i] = __builtin_nontemporal_load(p4 + (size_t)(batch * 8 + i) * 256);
#pragma unroll
        for (int i = 0; i < 8; ++i)
            G[i] = __builtin_nontemporal_load(g4 + (size_t)(batch * 8 + i) * 256);
#pragma unroll
        for (int i = 0; i < 8; ++i) {
            s_p += (P[i].x + P[i].y) + (P[i].z + P[i].w);
            s_t += (G[i].x + G[i].y) + (G[i].z + G[i].w);
            s_i += P[i].x * G[i].x + P[i].y * G[i].y + P[i].z * G[i].z + P[i].w * G[i].w;
        }
    }
    // Reduce the 8 lanes of each column-tile (lanes 8k..8k+7, same wave).
#pragma unroll
    for (int off = 4; off >= 1; off >>= 1) {
        s_p += __shfl_down(s_p, off, 64);
        s_t += __shfl_down(s_t, off, 64);
        s_i += __shfl_down(s_i, off, 64);
    }
    if ((t & 7) == 0) {
        const int ct = t >> 3;       // column-tile 0..31
        const int idx = b * (NBLK * NBLK) + strip * NBLK + ct;
        sp[idx] = s_p;
        st[idx] = s_t;
        si[idx] = s_i;
    }
}

// Kernel 2: one block per image; 961 windows each (4 iters/thread).
// Each block atomicAdds its partial (already divided by nwin) into out[0].
__global__ __launch_bounds__(256) void finalize_kernel(
    const float* __restrict__ sp, const float* __restrict__ st,
    const float* __restrict__ si, float* __restrict__ out, int B) {
    const int b = blockIdx.x;
    const int t = threadIdx.x;
    const int nwin = B * HO * WO;
    const int ibase = b * (NBLK * NBLK);
    float acc = 0.f;
    for (int w = t; w < HO * WO; w += 256) {
        const int i = w / WO;
        const int j = w - i * WO;
        const int base = ibase + i * NBLK + j;
        const float inter = (si[base] + si[base + 1]) + (si[base + NBLK] + si[base + NBLK + 1]);
        const float psum  = (sp[base] + sp[base + 1]) + (sp[base + NBLK] + sp[base + NBLK + 1]);
        const float tsum  = (st[base] + st[base + 1]) + (st[base + NBLK] + st[base + NBLK + 1]);
        const float uni = psum + tsum - inter;
        acc += 1.0f - (inter + EPSF) / (uni + EPSF);
    }
    // wave reduce
#pragma unroll
    for (int off = 32; off >= 1; off >>= 1) acc += __shfl_down(acc, off, 64);
    __shared__ float red[4];
    if ((t & 63) == 0) red[t >> 6] = acc;
    __syncthreads();
    if (t == 0) {
        const float s = (red[0] + red[1]) + (red[2] + red[3]);
        atomicAdd(out, s / (float)nwin);
    }
}

extern "C" void kernel_launch(void* const* d_in, const int* in_sizes, int n_in,
                              void* d_out, int out_size, void* d_ws, size_t ws_size,
                              hipStream_t stream) {
    const float* pred = (const float*)d_in[0];
    const float* targ = (const float*)d_in[1];
    float* out = (float*)d_out;

    const int B = in_sizes[0] / (Hdim * Wdim);   // 16
    const int nblocks = B * NBLK * NBLK;         // block sums per quantity

    float* sp = (float*)d_ws;
    float* st = sp + nblocks;
    float* si = st + nblocks;

    hipMemsetAsync(out, 0, sizeof(float), stream);
    block_sums_kernel<<<dim3(B * 32), dim3(256), 0, stream>>>(pred, targ, sp, st, si);
    finalize_kernel<<<dim3(B), dim3(256), 0, stream>>>(sp, st, si, out, B);
}

// Round 9
// 26.726 us; speedup vs baseline: 14.4814x; 1.1669x over previous
//
#include <hip/hip_runtime.h>
#include <hip/hip_bf16.h>

// PatchIoULoss: B=16, C=1, H=W=1024, patch 64x64, stride 32x32 -> Ho=Wo=31.
// Window(i,j) = sum of 2x2 group of non-overlapping 32x32 block sums.
// Two kernels. Read path measured pinned at ~5 TB/s for the dual-stream
// NT read (occupancy/cache-policy/layout all null). Finalize 16-wide with
// float atomicAdd; out[0] zeroed by kernel 1 (kernel boundary = coherence,
// no memset node). Do NOT fuse with per-block device fences (round 6: 10x).

#define Hdim 1024
#define Wdim 1024
#define NBLK 32          // 32x32 blocks per image per dim
#define HO 31
#define WO 31
#define EPSF 1e-7f

typedef float fx4 __attribute__((ext_vector_type(4)));

// Kernel 1: per-block(32x32) sums of pred, target, pred*target.
// grid = B * 32 strips = 512 blocks; 256 threads. Block sweeps its strip
// fully contiguously (128 KB per stream). NT loads staged 8-deep per
// stream (16 in flight/wave). Thread t's float4-col = t -> col-tile = t>>3
// (8 lanes/tile): full 32x32 block sums via 8-lane shuffle, no LDS.
__global__ __launch_bounds__(256) void block_sums_kernel(
    const float* __restrict__ pred, const float* __restrict__ targ,
    float* __restrict__ sp, float* __restrict__ st, float* __restrict__ si,
    float* __restrict__ out) {
    const int blk = blockIdx.x;      // 0..511
    const int b = blk >> 5;          // image
    const int strip = blk & 31;      // row-block 0..31
    const int t = threadIdx.x;       // 0..255 (= float4 column)

    if (blk == 0 && t == 0) out[0] = 0.f;   // replaces hipMemsetAsync node

    const size_t base4 = ((size_t)b * (Hdim * Wdim) + (size_t)strip * 32 * Wdim) / 4;
    const fx4* __restrict__ p4 = reinterpret_cast<const fx4*>(pred) + base4 + t;
    const fx4* __restrict__ g4 = reinterpret_cast<const fx4*>(targ) + base4 + t;

    float s_p = 0.f, s_t = 0.f, s_i = 0.f;
    for (int batch = 0; batch < 4; ++batch) {
        fx4 P[8], G[8];
#pragma unroll
        for (int i = 0; i < 8; ++i)
            P[i] = __builtin_nontemporal_load(p4 + (size_t)(batch * 8 + i) * 256);
#pragma unroll
        for (int i = 0; i < 8; ++i)
            G[i] = __builtin_nontemporal_load(g4 + (size_t)(batch * 8 + i) * 256);
#pragma unroll
        for (int i = 0; i < 8; ++i) {
            s_p += (P[i].x + P[i].y) + (P[i].z + P[i].w);
            s_t += (G[i].x + G[i].y) + (G[i].z + G[i].w);
            s_i += P[i].x * G[i].x + P[i].y * G[i].y + P[i].z * G[i].z + P[i].w * G[i].w;
        }
    }
    // Reduce the 8 lanes of each column-tile (lanes 8k..8k+7, same wave).
#pragma unroll
    for (int off = 4; off >= 1; off >>= 1) {
        s_p += __shfl_down(s_p, off, 64);
        s_t += __shfl_down(s_t, off, 64);
        s_i += __shfl_down(s_i, off, 64);
    }
    if ((t & 7) == 0) {
        const int ct = t >> 3;       // column-tile 0..31
        const int idx = b * (NBLK * NBLK) + strip * NBLK + ct;
        sp[idx] = s_p;
        st[idx] = s_t;
        si[idx] = s_i;
    }
}

// Kernel 2: one block per image; 961 windows each (4 iters/thread).
// Each block atomicAdds its partial (already divided by nwin) into out[0].
__global__ __launch_bounds__(256) void finalize_kernel(
    const float* __restrict__ sp, const float* __restrict__ st,
    const float* __restrict__ si, float* __restrict__ out, int B) {
    const int b = blockIdx.x;
    const int t = threadIdx.x;
    const int nwin = B * HO * WO;
    const int ibase = b * (NBLK * NBLK);
    float acc = 0.f;
    for (int w = t; w < HO * WO; w += 256) {
        const int i = w / WO;
        const int j = w - i * WO;
        const int base = ibase + i * NBLK + j;
        const float inter = (si[base] + si[base + 1]) + (si[base + NBLK] + si[base + NBLK + 1]);
        const float psum  = (sp[base] + sp[base + 1]) + (sp[base + NBLK] + sp[base + NBLK + 1]);
        const float tsum  = (st[base] + st[base + 1]) + (st[base + NBLK] + st[base + NBLK + 1]);
        const float uni = psum + tsum - inter;
        acc += 1.0f - (inter + EPSF) / (uni + EPSF);
    }
    // wave reduce
#pragma unroll
    for (int off = 32; off >= 1; off >>= 1) acc += __shfl_down(acc, off, 64);
    __shared__ float red[4];
    if ((t & 63) == 0) red[t >> 6] = acc;
    __syncthreads();
    if (t == 0) {
        const float s = (red[0] + red[1]) + (red[2] + red[3]);
        atomicAdd(out, s / (float)nwin);
    }
}

extern "C" void kernel_launch(void* const* d_in, const int* in_sizes, int n_in,
                              void* d_out, int out_size, void* d_ws, size_t ws_size,
                              hipStream_t stream) {
    const float* pred = (const float*)d_in[0];
    const float* targ = (const float*)d_in[1];
    float* out = (float*)d_out;

    const int B = in_sizes[0] / (Hdim * Wdim);   // 16
    const int nblocks = B * NBLK * NBLK;         // block sums per quantity

    float* sp = (float*)d_ws;
    float* st = sp + nblocks;
    float* si = st + nblocks;

    block_sums_kernel<<<dim3(B * 32), dim3(256), 0, stream>>>(pred, targ, sp, st, si, out);
    finalize_kernel<<<dim3(B), dim3(256), 0, stream>>>(sp, st, si, out, B);
}

// Round 10
// 25.990 us; speedup vs baseline: 14.8914x; 1.0283x over previous
//
#include <hip/hip_runtime.h>
#include <hip/hip_bf16.h>

// PatchIoULoss: B=16, C=1, H=W=1024, patch 64x64, stride 32x32 -> Ho=Wo=31.
// Window(i,j) = sum of 2x2 group of non-overlapping 32x32 block sums.
// Two kernels. Read path measured pinned at ~6 TB/s for the dual-stream
// NT read (occupancy/cache-policy/layout experiments all null). Finalize:
// one window per thread, per-block atomicAdd; out[0] zeroed by kernel 1
// (kernel boundary = coherence point, no memset node: a graph node costs
// ~4.5 us). Do NOT fuse with per-block device fences (round 6: 10x).

#define Hdim 1024
#define Wdim 1024
#define NBLK 32          // 32x32 blocks per image per dim
#define HO 31
#define WO 31
#define EPSF 1e-7f

typedef float fx4 __attribute__((ext_vector_type(4)));

// Kernel 1: per-block(32x32) sums of pred, target, pred*target.
// grid = B * 32 strips = 512 blocks; 256 threads. Block sweeps its strip
// fully contiguously (128 KB per stream). NT loads staged 8-deep per
// stream (16 in flight/wave). Thread t's float4-col = t -> col-tile = t>>3
// (8 lanes/tile): full 32x32 block sums via 8-lane shuffle, no LDS.
__global__ __launch_bounds__(256) void block_sums_kernel(
    const float* __restrict__ pred, const float* __restrict__ targ,
    float* __restrict__ sp, float* __restrict__ st, float* __restrict__ si,
    float* __restrict__ out) {
    const int blk = blockIdx.x;      // 0..511
    const int b = blk >> 5;          // image
    const int strip = blk & 31;      // row-block 0..31
    const int t = threadIdx.x;       // 0..255 (= float4 column)

    if (blk == 0 && t == 0) out[0] = 0.f;   // replaces hipMemsetAsync node

    const size_t base4 = ((size_t)b * (Hdim * Wdim) + (size_t)strip * 32 * Wdim) / 4;
    const fx4* __restrict__ p4 = reinterpret_cast<const fx4*>(pred) + base4 + t;
    const fx4* __restrict__ g4 = reinterpret_cast<const fx4*>(targ) + base4 + t;

    float s_p = 0.f, s_t = 0.f, s_i = 0.f;
    for (int batch = 0; batch < 4; ++batch) {
        fx4 P[8], G[8];
#pragma unroll
        for (int i = 0; i < 8; ++i)
            P[i] = __builtin_nontemporal_load(p4 + (size_t)(batch * 8 + i) * 256);
#pragma unroll
        for (int i = 0; i < 8; ++i)
            G[i] = __builtin_nontemporal_load(g4 + (size_t)(batch * 8 + i) * 256);
#pragma unroll
        for (int i = 0; i < 8; ++i) {
            s_p += (P[i].x + P[i].y) + (P[i].z + P[i].w);
            s_t += (G[i].x + G[i].y) + (G[i].z + G[i].w);
            s_i += P[i].x * G[i].x + P[i].y * G[i].y + P[i].z * G[i].z + P[i].w * G[i].w;
        }
    }
    // Reduce the 8 lanes of each column-tile (lanes 8k..8k+7, same wave).
#pragma unroll
    for (int off = 4; off >= 1; off >>= 1) {
        s_p += __shfl_down(s_p, off, 64);
        s_t += __shfl_down(s_t, off, 64);
        s_i += __shfl_down(s_i, off, 64);
    }
    if ((t & 7) == 0) {
        const int ct = t >> 3;       // column-tile 0..31
        const int idx = b * (NBLK * NBLK) + strip * NBLK + ct;
        sp[idx] = s_p;
        st[idx] = s_t;
        si[idx] = s_i;
    }
}

// Kernel 2: ONE WINDOW PER THREAD. nwin = B*31*31 = 15376 windows ->
// 61 blocks x 256 threads; each block reduces and does one atomicAdd.
__global__ __launch_bounds__(256) void finalize_kernel(
    const float* __restrict__ sp, const float* __restrict__ st,
    const float* __restrict__ si, float* __restrict__ out, int B) {
    const int t = threadIdx.x;
    const int w = blockIdx.x * 256 + t;
    const int nwin = B * HO * WO;
    float acc = 0.f;
    if (w < nwin) {
        const int b = w / (HO * WO);
        const int rem = w - b * (HO * WO);
        const int i = rem / WO;
        const int j = rem - i * WO;
        const int base = b * (NBLK * NBLK) + i * NBLK + j;
        const float inter = (si[base] + si[base + 1]) + (si[base + NBLK] + si[base + NBLK + 1]);
        const float psum  = (sp[base] + sp[base + 1]) + (sp[base + NBLK] + sp[base + NBLK + 1]);
        const float tsum  = (st[base] + st[base + 1]) + (st[base + NBLK] + st[base + NBLK + 1]);
        const float uni = psum + tsum - inter;
        acc = 1.0f - (inter + EPSF) / (uni + EPSF);
    }
    // wave reduce
#pragma unroll
    for (int off = 32; off >= 1; off >>= 1) acc += __shfl_down(acc, off, 64);
    __shared__ float red[4];
    if ((t & 63) == 0) red[t >> 6] = acc;
    __syncthreads();
    if (t == 0) {
        const float s = (red[0] + red[1]) + (red[2] + red[3]);
        atomicAdd(out, s / (float)nwin);
    }
}

extern "C" void kernel_launch(void* const* d_in, const int* in_sizes, int n_in,
                              void* d_out, int out_size, void* d_ws, size_t ws_size,
                              hipStream_t stream) {
    const float* pred = (const float*)d_in[0];
    const float* targ = (const float*)d_in[1];
    float* out = (float*)d_out;

    const int B = in_sizes[0] / (Hdim * Wdim);   // 16
    const int nblocks = B * NBLK * NBLK;         // block sums per quantity
    const int nwin = B * HO * WO;                // 15376

    float* sp = (float*)d_ws;
    float* st = sp + nblocks;
    float* si = st + nblocks;

    block_sums_kernel<<<dim3(B * 32), dim3(256), 0, stream>>>(pred, targ, sp, st, si, out);
    finalize_kernel<<<dim3((nwin + 255) / 256), dim3(256), 0, stream>>>(sp, st, si, out, B);
}